// Round 4
// baseline (59.443 us; speedup 1.0000x reference)
//
#include <hip/hip_runtime.h>
#include <math.h>

#define N_WIRES 18
#define BATCH 64

// Closed-form evaluation of the quantum circuit (derivation verified: absmax 0.0
// in rounds 1-3):
//   theta[b,i] = (a[b,i]-min)/(max-min)*2pi - pi      (min/max over whole batch)
//   <Z_i>      = cos(alpha_i)cos(beta_i)cos(theta_i)
//                - sin(beta_i)sin(theta_i)*cos(theta_{i-1})*cos(theta_{i+1})
//   out[b]     = head_b + sum_i head_w[i]*<Z_i>
//
// Round-4 structure: ONE wave, one batch row per lane, ZERO LDS, ZERO barriers.
// Per-wire coefficients use uniform (compile-time-indexed kernel-arg) addresses
// -> compiler emits s_load into SGPRs; every lane redundantly computes the 18
// coefficient pairs with inline __cosf/__sinf (~220 cyc) while the 18 row
// loads are in flight. This removes round-3's divergent t<18 path, the LDS
// round-trip, and the __syncthreads/lgkmcnt stall -- the last few us of
// kernel-controllable time. Timeline is otherwise pinned by the harness's
// 268 MB poison fill (39.5 us @ 85% HBM peak).
__global__ __launch_bounds__(64) void qc_closed_form(
        const float* __restrict__ a,       // (BATCH, N_WIRES)
        const float* __restrict__ params,  // (N_WIRES, 3)
        const float* __restrict__ head_w,  // (1, N_WIRES)
        const float* __restrict__ head_b,  // (1,)
        float* __restrict__ out)           // (BATCH,)
{
    const int t = threadIdx.x;  // 0..63 == batch row

    // ---- issue the 18 row loads first (independent, stay in flight) ----
    float v[N_WIRES];
    const float* row = a + t * N_WIRES;
    #pragma unroll
    for (int i = 0; i < N_WIRES; ++i) v[i] = row[i];

    // ---- per-wire coefficients from uniform scalar loads (hides vmcnt) ----
    // cA_i = cos(alpha)cos(beta)*w_i ; cB_i = sin(beta)*w_i
    float cA[N_WIRES], cB[N_WIRES];
    #pragma unroll
    for (int i = 0; i < N_WIRES; ++i) {
        float al = params[3 * i];
        float be = params[3 * i + 1];
        float w  = head_w[i];
        cA[i] = __cosf(al) * __cosf(be) * w;
        cB[i] = __sinf(be) * w;
    }
    float acc = head_b[0];  // scalar load, folded into accumulator init

    // ---- global min/max: in-register over the row, then wave-64 butterfly ----
    float mn = v[0], mx = v[0];
    #pragma unroll
    for (int i = 1; i < N_WIRES; ++i) {
        mn = fminf(mn, v[i]);
        mx = fmaxf(mx, v[i]);
    }
    #pragma unroll
    for (int off = 32; off > 0; off >>= 1) {
        mn = fminf(mn, __shfl_xor(mn, off));
        mx = fmaxf(mx, __shfl_xor(mx, off));
    }
    const float scale = 6.28318530717958647692f / (mx - mn);
    const float pi    = 3.14159265358979323846f;

    // ---- angles -> cos/sin in registers (18 independent chains, good ILP) ----
    float ct[N_WIRES], st[N_WIRES];
    #pragma unroll
    for (int i = 0; i < N_WIRES; ++i) {
        float th = (v[i] - mn) * scale - pi;
        ct[i] = __cosf(th);
        st[i] = __sinf(th);
    }

    // ---- closed-form accumulation ----
    #pragma unroll
    for (int i = 0; i < N_WIRES; ++i) {
        float cl = (i == 0)           ? 1.0f : ct[i - 1];
        float cr = (i == N_WIRES - 1) ? 1.0f : ct[i + 1];
        acc = fmaf(cA[i], ct[i], acc);
        acc -= cB[i] * st[i] * cl * cr;
    }
    out[t] = acc;
}

extern "C" void kernel_launch(void* const* d_in, const int* in_sizes, int n_in,
                              void* d_out, int out_size, void* d_ws, size_t ws_size,
                              hipStream_t stream) {
    const float* a      = (const float*)d_in[0];  // state_batch (64,18)
    const float* params = (const float*)d_in[1];  // (18,3)
    const float* head_w = (const float*)d_in[2];  // (1,18)
    const float* head_b = (const float*)d_in[3];  // (1,)
    float* out = (float*)d_out;                   // (64,)
    qc_closed_form<<<1, 64, 0, stream>>>(a, params, head_w, head_b, out);
}